// Round 9
// baseline (382.446 us; speedup 1.0000x reference)
//
#include <hip/hip_runtime.h>

// DynamicRouting (CapsNet) on MI355X — single persistent kernel + tiny memset.
// B=16, I=32, C=8, J=10, D=16, H=W=6 -> DHW=576. num_routing=3 (fixed).
//
// Algebra: c[i,j] broadcasts over C and v is (i,c)-independent:
//   U[b,i,j,:] = sum_c u_hat[b,i,c,j,:]           (11.8 MB, one HBM pass)
//   s_r        = sum_i c_r[i,j] U + bias
//   agreement_r[i,j] = sum_b sc_r[b] * G_r[b,i,j],  G_r = sum_dhw U*s_r
//
// Structure: 480 blocks x 256 threads (co-resident: 1920 waves, 26KB LDS).
//   phase 0: grid-stride float4 channel reduce -> U2 global (full device)
//   barrier; each block = one (b,j,chunk) tile: 192 dhw x 32 i, staged once
//   into LDS (stride 193) and reused for all 3 iterations. n1/G partials
//   combine via f64 atomicAdd into memset-zeroed slots.
// Bug history: R7 = U2 overlapped Gp in ws (fixed R8) AND the b_ij fold used
// `if (tid < 320)` with only 256 threads -> rows i>=25 of the logits were
// uninitialized LDS (fixed here: strided loop).

#define NB   16
#define NI   32
#define NC   8
#define NJ   10
#define ND   16
#define NHW  36
#define NDHW 576
#define EPSV 1e-7f
#define TPB  256
#define NBLK 480                   // 160 (b,j) tiles x 3 chunks
#define CHUNK 192                  // dhw per block
#define LSTR 193                   // padded LDS leading stride

static __device__ __forceinline__ double wave_sum64(double v) {
    #pragma unroll
    for (int off = 32; off > 0; off >>= 1) v += __shfl_down(v, off);
    return v;
}

// grid barrier: cnt/rel memset-zeroed before launch. Arrivers' threadfence +
// ACQ_REL RMW release prior plain stores; last arriver sets rel; spinners
// acquire it. Proven under graph replay in R6.
static __device__ __forceinline__ void grid_barrier(unsigned* cnt,
                                                    unsigned* rel, int tid) {
    __syncthreads();
    if (tid == 0) {
        __threadfence();
        unsigned old = __hip_atomic_fetch_add(cnt, 1u, __ATOMIC_ACQ_REL,
                                              __HIP_MEMORY_SCOPE_AGENT);
        if (old == NBLK - 1) {
            __hip_atomic_store(rel, 1u, __ATOMIC_RELEASE,
                               __HIP_MEMORY_SCOPE_AGENT);
        } else {
            while (__hip_atomic_load(rel, __ATOMIC_ACQUIRE,
                                     __HIP_MEMORY_SCOPE_AGENT) == 0u)
                __builtin_amdgcn_s_sleep(8);
        }
    }
    __syncthreads();
}

__global__ __launch_bounds__(TPB) void mega_kernel(
    const float4* __restrict__ uh4, const float* __restrict__ bias,
    float4* __restrict__ U2f4, double* __restrict__ n1p,
    double* __restrict__ Gp, unsigned* __restrict__ bar,
    float* __restrict__ out)
{
    __shared__ float  Utile[NI * LSTR];    // 24.1 KB: [i][dhw-in-chunk]
    __shared__ float  s_sh[CHUNK];
    __shared__ double sc_sh[2][NB];
    __shared__ float  bij_sh[NI * NJ];
    __shared__ float  c_sh[NI];

    const int blk = blockIdx.x;
    const int tile  = blk / 3;             // b*NJ + j
    const int chunk = blk - tile * 3;      // 0..2
    const int b = tile / NJ, j = tile - b * NJ;
    const int tid = threadIdx.x;

    // ---------------- phase 0: U2 = sum_c u_hat (full device) ----------------
    // output float4 index t: ((b*10+j)*32+i)*144 + f4 ; 737280 = NBLK*TPB*6.
    #pragma unroll
    for (int it = 0; it < 6; ++it) {
        int t  = it * (NBLK * TPB) + blk * TPB + tid;
        int f4 = t % 144;
        int i  = (t / 144) % NI;
        int jj = (t / (144 * NI)) % NJ;
        int bb = t / (144 * NI * NJ);
        const float4* p = uh4 + ((size_t)(bb * NI + i) * NC) * 1440 + jj * 144 + f4;
        float4 acc = make_float4(0.f, 0.f, 0.f, 0.f);
        #pragma unroll
        for (int c = 0; c < NC; ++c) {
            float4 v = p[(size_t)c * 1440];
            acc.x += v.x; acc.y += v.y; acc.z += v.z; acc.w += v.w;
        }
        U2f4[t] = acc;
    }
    grid_barrier(&bar[0], &bar[4], tid);

    // ---------------- stage this block's tile into LDS ----------------
    // Utile[i][t] = U2[((b*10+j)*32+i)*576 + chunk*192 + t], t<192
    {
        const float* U2 = (const float*)U2f4;
        const float* src = U2 + (size_t)tile * NI * NDHW + chunk * CHUNK;
        if (tid < CHUNK) {
            #pragma unroll 8
            for (int i = 0; i < NI; ++i)
                Utile[i * LSTR + tid] = src[i * NDHW + tid];
        }
    }
    __syncthreads();

    const float bias_v = (tid < CHUNK)
        ? bias[j * ND + (chunk * CHUNK + tid) / NHW] : 0.f;

    for (int r = 0; r < 3; ++r) {
        // ---- coupling coefficients ----
        if (r == 0) {
            if (tid < NI) c_sh[tid] = 0.1f;    // softmax of zeros
            __syncthreads();
        } else {
            if (tid < r * NB) {
                int rr = tid / NB, bb = tid - rr * NB;
                double n1v = n1p[rr * NB + bb];
                double nsq = n1v * n1v;
                sc_sh[rr][bb] = (nsq / (1.0 + nsq)) / (n1v + (double)EPSV);
            }
            __syncthreads();
            // NOTE: NI*NJ = 320 > TPB -> strided loop (R7/R8 bug was a
            // plain `if (tid < 320)` guard leaving rows i>=25 uninitialized)
            for (int t = tid; t < NI * NJ; t += TPB) {
                int i = t / NJ, jj = t - i * NJ;
                double a = 0.0;
                for (int rr = 0; rr < r; ++rr)
                    #pragma unroll
                    for (int bb = 0; bb < NB; ++bb)
                        a += sc_sh[rr][bb] *
                             Gp[(size_t)rr * (NB * NJ * NI) +
                                (size_t)(bb * NJ + jj) * NI + i];
                bij_sh[t] = (float)a;
            }
            __syncthreads();
            if (tid < NI) {
                float m = -1e30f;
                #pragma unroll
                for (int jj = 0; jj < NJ; ++jj)
                    m = fmaxf(m, bij_sh[tid * NJ + jj]);
                float sum = 0.f;
                #pragma unroll
                for (int jj = 0; jj < NJ; ++jj)
                    sum += expf(bij_sh[tid * NJ + jj] - m);
                c_sh[tid] = expf(bij_sh[tid * NJ + j] - m) / sum;
            }
            __syncthreads();
        }

        // ---- s pass (192 threads, LDS conflict-free) ----
        if (tid < CHUNK) {
            float sv = bias_v;
            #pragma unroll
            for (int i = 0; i < NI; ++i)
                sv += c_sh[i] * Utile[i * LSTR + tid];
            s_sh[tid] = sv;
        }
        __syncthreads();

        // ---- n1[b] += sum |s| (wave 0 reduces the 192 values) ----
        if (tid < 64) {
            double a = (double)fabsf(s_sh[tid]) +
                       (double)fabsf(s_sh[tid + 64]) +
                       (double)fabsf(s_sh[tid + 128]);
            a = wave_sum64(a);
            if (tid == 0)
                atomicAdd(&n1p[r * NB + b], a);
        }

        // ---- G[b,i,j] += dot(U[i,:], s) ; (i,k) = 32x8 decomposition ----
        if (r < 2) {
            int i = tid >> 3, k = tid & 7;
            const float* Ui = &Utile[i * LSTR + k * 24];
            const float* sk = &s_sh[k * 24];
            double p = 0.0;
            #pragma unroll
            for (int m = 0; m < 24; ++m)
                p += (double)Ui[m] * (double)sk[m];
            p += __shfl_down(p, 4);
            p += __shfl_down(p, 2);
            p += __shfl_down(p, 1);
            if (k == 0)
                atomicAdd(&Gp[(size_t)r * (NB * NJ * NI) +
                              (size_t)(b * NJ + j) * NI + i], p);
        }
        grid_barrier(&bar[1 + r], &bar[5 + r], tid);
    }

    // ---- v = (n1^2/(1+n1^2)) * (s/(n1+eps)) ----
    if (tid < CHUNK) {
        float n1f = (float)n1p[2 * NB + b];
        float nsq = n1f * n1f;
        out[(size_t)tile * NDHW + chunk * CHUNK + tid] =
            (nsq / (1.f + nsq)) * (s_sh[tid] / (n1f + EPSV));
    }
}

extern "C" void kernel_launch(void* const* d_in, const int* in_sizes, int n_in,
                              void* d_out, int out_size, void* d_ws, size_t ws_size,
                              hipStream_t stream)
{
    const float* u_hat = (const float*)d_in[0];
    const float* bias  = (const float*)d_in[1];
    // d_in[2] = num_routing, fixed at 3 by the problem.

    // ws layout (non-overlapping):
    //   [0,      64)   bar: 8 u32
    //   [64,    448)   n1p: 3*16 doubles
    //   [448, 82368)   Gp : 2*160*32 doubles
    //   [131072, 131072+11796480)  U2: 16*10*32*576 floats
    unsigned* bar = (unsigned*)d_ws;
    double*   n1p = (double*)((char*)d_ws + 64);
    double*   Gp  = (double*)((char*)d_ws + 448);
    float*    U2  = (float*)((char*)d_ws + 131072);
    float*    out = (float*)d_out;

    // zero barrier slots + n1/G accumulators (d_ws is 0xAA-poisoned each call)
    hipMemsetAsync(d_ws, 0, 448 + 2 * NB * NJ * NI * sizeof(double), stream);
    mega_kernel<<<NBLK, TPB, 0, stream>>>(
        (const float4*)u_hat, bias, (float4*)U2, n1p, Gp, bar, out);
}

// Round 10
// 183.088 us; speedup vs baseline: 2.0889x; 2.0889x over previous
//
#include <hip/hip_runtime.h>

// DynamicRouting (CapsNet) on MI355X — 5-kernel pipeline, no barriers/atomics.
// B=16, I=32, C=8, J=10, D=16, H=W=6 -> DHW=576. num_routing=3 (fixed).
//
// Algebra: c[i,j] broadcasts over C and v is (i,c)-independent:
//   U[b,i,j,:] = sum_c u_hat[b,i,c,j,:]           (11.8 MB, one HBM pass)
//   s_r        = sum_i c_r[i,j] U + bias
//   agreement_r[i,j] = sum_b sc_r[b] * G_r[b,i,j],  G_r = sum_dhw U*s_r
// Each iteration kernel emits per-(b,j) n1/G partials; the NEXT kernel's
// prologue redundantly folds them into sc -> b_ij -> softmax -> c[:,j].
// Iteration 0: b_ij=0 -> c = 0.1 exactly.
//
// Lessons encoded here:
//  * In-kernel grid barriers cost ~125ns PER BLOCK on this part (R2/R6/R9) —
//    use kernel boundaries as barriers instead.
//  * R4's "replay divergence" was a ws overrun (12.25MB footprint): keep the
//    total ws footprint at R9's proven 11.93MB. Hence no stored s: the final
//    kernel re-folds c2 and recomputes s (cheap L2 reads).
//  * The 94.4MB u_hat pass needs full-device parallelism (2880 blocks);
//    160-block versions latency-crawl (R5/R6).

#define NB   16
#define NI   32
#define NC   8
#define NJ   10
#define ND   16
#define NHW  36
#define NDHW 576
#define EPSV 1e-7f
#define TPB  576                   // 9 waves; one thread per dhw

// U2 layout [b][j][i][dhw]: strides (floats) b:184320  j:18432  i:576

static __device__ __forceinline__ double wave_sum(double v) {
    #pragma unroll
    for (int off = 32; off > 0; off >>= 1) v += __shfl_down(v, off);
    return v;
}

// block-reduce |sv| over 576 threads -> slot (thread 0 writes)
static __device__ __forceinline__ void n1_reduce(float sv, double* slot,
                                                 double* nred /*[9]*/) {
    int tid = threadIdx.x;
    double a = wave_sum((double)fabsf(sv));
    if ((tid & 63) == 0) nred[tid >> 6] = a;
    __syncthreads();
    if (tid == 0) {
        double t = nred[0];
        #pragma unroll
        for (int w = 1; w < 9; ++w) t += nred[w];
        *slot = t;
    }
}

// block-reduce Uv[i]*sv over 576 threads for all 32 i -> gslot[i]
static __device__ __forceinline__ void g_reduce(const float* Uv, float sv,
                                                double* gslot,
                                                double (*gred)[32] /*[9][32]*/) {
    int tid = threadIdx.x, w = tid >> 6, lane = tid & 63;
    #pragma unroll
    for (int i = 0; i < NI; ++i) {
        double p = wave_sum((double)Uv[i] * (double)sv);
        if (lane == 0) gred[w][i] = p;
    }
    __syncthreads();
    if (tid < NI) {
        double t = gred[0][tid];
        #pragma unroll
        for (int w2 = 1; w2 < 9; ++w2) t += gred[w2][tid];
        gslot[tid] = t;
    }
}

// fold prologue: rebuild c[:,j] for iteration R from n1/G partials of 0..R-1.
// All guards valid for TPB=576 (NI*NJ=320 < 576).
static __device__ __forceinline__ void fold_c(
    int R, int j, int tid,
    const double* __restrict__ n1p, const double* __restrict__ Gp,
    double (*sc_sh)[NB], float* bij_sh, float* c_sh)
{
    if (tid < R * NB) {
        int rr = tid / NB, bb = tid - rr * NB;
        double n1 = 0.0;
        #pragma unroll
        for (int jj = 0; jj < NJ; ++jj) n1 += n1p[rr * (NB * NJ) + bb * NJ + jj];
        double nsq = n1 * n1;
        sc_sh[rr][bb] = (nsq / (1.0 + nsq)) / (n1 + (double)EPSV);
    }
    __syncthreads();
    if (tid < NI * NJ) {
        int i = tid / NJ, jj = tid - i * NJ;
        double a = 0.0;
        for (int rr = 0; rr < R; ++rr)
            #pragma unroll
            for (int bb = 0; bb < NB; ++bb)
                a += sc_sh[rr][bb] *
                     Gp[(size_t)(rr * NB + bb) * NJ * NI + (size_t)jj * NI + i];
        bij_sh[tid] = (float)a;
    }
    __syncthreads();
    if (tid < NI) {
        float m = -1e30f;
        #pragma unroll
        for (int jj = 0; jj < NJ; ++jj) m = fmaxf(m, bij_sh[tid * NJ + jj]);
        float sum = 0.f;
        #pragma unroll
        for (int jj = 0; jj < NJ; ++jj) sum += expf(bij_sh[tid * NJ + jj] - m);
        c_sh[tid] = expf(bij_sh[tid * NJ + j] - m) / sum;
    }
    __syncthreads();
}

// ---------------------------------------------------------------------------
// Kernel 1: pure channel reduce, float4, 2880 blocks (full device).
// Output U2[b][j][i][dhw]; t is the OUTPUT float4 index.
// ---------------------------------------------------------------------------
__global__ __launch_bounds__(256) void reduce_c_kernel(
    const float4* __restrict__ uh, float4* __restrict__ U2)
{
    int t = blockIdx.x * 256 + threadIdx.x;     // < 16*10*32*144 = 737280
    int f4 = t % 144;
    int i  = (t / 144) % NI;
    int j  = (t / (144 * NI)) % NJ;
    int b  = t / (144 * NI * NJ);
    // u_hat float4 index: ((b*NI+i)*NC + c)*1440 + j*144 + f4
    const float4* p = uh + ((size_t)(b * NI + i) * NC) * 1440 + j * 144 + f4;
    float4 acc = make_float4(0.f, 0.f, 0.f, 0.f);
    #pragma unroll
    for (int c = 0; c < NC; ++c) {
        float4 v = p[(size_t)c * 1440];
        acc.x += v.x; acc.y += v.y; acc.z += v.z; acc.w += v.w;
    }
    U2[t] = acc;
}

// ---------------------------------------------------------------------------
// Kernel 2: iteration 0 (b_ij=0 -> c = 0.1 exactly). U2 from L2/L3.
// ---------------------------------------------------------------------------
__global__ __launch_bounds__(TPB) void b0_kernel(
    const float* __restrict__ U2, const float* __restrict__ bias,
    double* __restrict__ n1p, double* __restrict__ Gp)
{
    __shared__ double nred[9];
    __shared__ double gred[9][32];

    const int blk = blockIdx.x;            // b*NJ + j
    const int b = blk / NJ, j = blk - b * NJ;
    const int tid = threadIdx.x;           // dhw

    const float* u2b = U2 + (size_t)b * 184320 + j * 18432 + tid;
    float Uv[NI];
    float sv = bias[j * ND + tid / NHW];
    #pragma unroll
    for (int i = 0; i < NI; ++i) {
        Uv[i] = u2b[i * 576];
        sv += 0.1f * Uv[i];
    }

    n1_reduce(sv, &n1p[blk], nred);
    g_reduce(Uv, sv, &Gp[(size_t)blk * NI], gred);
}

// ---------------------------------------------------------------------------
// Kernel 3/4: iteration R (R=1,2). R=1 emits n1p[1]+Gp[1]; R=2 emits n1p[2].
// ---------------------------------------------------------------------------
template <int R>
__global__ __launch_bounds__(TPB) void ab_kernel(
    const float* __restrict__ U2, const float* __restrict__ bias,
    const double* __restrict__ n1p, double* __restrict__ Gp,
    double* __restrict__ n1p_out, double* __restrict__ Gp_out)
{
    __shared__ double sc_sh[2][NB];
    __shared__ float  bij_sh[NI * NJ];
    __shared__ float  c_sh[NI];
    __shared__ double nred[9];
    __shared__ double gred[9][32];

    const int blk = blockIdx.x;            // b*NJ + j
    const int b = blk / NJ, j = blk - b * NJ;
    const int tid = threadIdx.x;           // dhw

    fold_c(R, j, tid, n1p, Gp, sc_sh, bij_sh, c_sh);

    const float* u2b = U2 + (size_t)b * 184320 + j * 18432 + tid;
    float Uv[NI];
    float sv = bias[j * ND + tid / NHW];
    #pragma unroll
    for (int i = 0; i < NI; ++i) {
        Uv[i] = u2b[i * 576];
        sv += c_sh[i] * Uv[i];
    }

    n1_reduce(sv, &n1p_out[blk], nred);
    if (R == 1)
        g_reduce(Uv, sv, &Gp_out[(size_t)blk * NI], gred);
}

// ---------------------------------------------------------------------------
// Kernel 5: re-fold c2, recompute s2, scale by final n1 -> out.
// (s is never stored to ws: keeps total footprint at the proven 11.93 MB.)
// ---------------------------------------------------------------------------
__global__ __launch_bounds__(TPB) void vfold_kernel(
    const float* __restrict__ U2, const float* __restrict__ bias,
    const double* __restrict__ n1p, const double* __restrict__ Gp,
    const double* __restrict__ n1p2, float* __restrict__ out)
{
    __shared__ double sc_sh[2][NB];
    __shared__ float  bij_sh[NI * NJ];
    __shared__ float  c_sh[NI];

    const int blk = blockIdx.x;            // b*NJ + j
    const int b = blk / NJ, j = blk - b * NJ;
    const int tid = threadIdx.x;           // dhw

    fold_c(2, j, tid, n1p, Gp, sc_sh, bij_sh, c_sh);

    const float* u2b = U2 + (size_t)b * 184320 + j * 18432 + tid;
    float sv = bias[j * ND + tid / NHW];
    #pragma unroll
    for (int i = 0; i < NI; ++i)
        sv += c_sh[i] * u2b[i * 576];

    double n1 = 0.0;
    #pragma unroll
    for (int jj = 0; jj < NJ; ++jj) n1 += n1p2[b * NJ + jj];
    float n1f = (float)n1;
    float nsq = n1f * n1f;
    out[(size_t)blk * NDHW + tid] = (nsq / (1.f + nsq)) * (sv / (n1f + EPSV));
}

extern "C" void kernel_launch(void* const* d_in, const int* in_sizes, int n_in,
                              void* d_out, int out_size, void* d_ws, size_t ws_size,
                              hipStream_t stream)
{
    const float* u_hat = (const float*)d_in[0];
    const float* bias  = (const float*)d_in[1];
    // d_in[2] = num_routing, fixed at 3 by the problem.

    // ws layout (total 11,927,552 B — R9-proven footprint; R4 overran ws):
    //   [0,      3840)  n1p: 3*160 doubles (per-(b,j) partials)
    //   [3840,  85760)  Gp : 2*160*32 doubles
    //   [131072, 131072+11796480)  U2: 16*10*32*576 floats
    double* n1p = (double*)d_ws;
    double* Gp  = (double*)((char*)d_ws + 3840);
    float*  U2  = (float*)((char*)d_ws + 131072);
    float*  out = (float*)d_out;

    reduce_c_kernel<<<737280 / 256, 256, 0, stream>>>(
        (const float4*)u_hat, (float4*)U2);
    b0_kernel<<<NB * NJ, TPB, 0, stream>>>(U2, bias, n1p, Gp);
    ab_kernel<1><<<NB * NJ, TPB, 0, stream>>>(
        U2, bias, n1p, Gp, n1p + NB * NJ, Gp + NB * NJ * NI);
    ab_kernel<2><<<NB * NJ, TPB, 0, stream>>>(
        U2, bias, n1p, Gp, n1p + 2 * NB * NJ, nullptr);
    vfold_kernel<<<NB * NJ, TPB, 0, stream>>>(
        U2, bias, n1p, Gp, n1p + 2 * NB * NJ, out);
}